// Round 1
// baseline (638.380 us; speedup 1.0000x reference)
//
#include <hip/hip_runtime.h>
#include <math.h>

// ---------- types ----------
typedef short short8_t __attribute__((ext_vector_type(8)));
typedef __bf16 bf16x8_t __attribute__((ext_vector_type(8)));
typedef float f32x4_t __attribute__((ext_vector_type(4)));

__device__ __forceinline__ float bf2f(unsigned short u) {
  unsigned v = ((unsigned)u) << 16;
  return __builtin_bit_cast(float, v);
}
__device__ __forceinline__ unsigned short f2bf(float f) {
  unsigned x = __builtin_bit_cast(unsigned, f);
  x += 0x7fffu + ((x >> 16) & 1u);
  return (unsigned short)(x >> 16);
}

// ---------- constants ----------
// B=4, Na=Nb=8192, D=256, TOPK=8, FULL_SCALE=128, R=0.5
#define NA 8192
#define NB 8192
#define NBATCH 4
#define DIM 256
#define NPTS (NBATCH * NA)   // 32768
#define KSLICES 8
#define SLICE_LEN (NB / KSLICES)  // 1024

// ---------- prep: weights to bf16 ----------
__global__ __launch_bounds__(256) void prep_weights(
    const float* __restrict__ w1, const float* __restrict__ w2,
    unsigned short* __restrict__ Wdiff, unsigned short* __restrict__ Wb,
    unsigned short* __restrict__ W2b) {
  int d = blockIdx.x, t = threadIdx.x;
  float wa = w1[d * 512 + t];
  float wb = w1[d * 512 + 256 + t];
  Wdiff[d * 256 + t] = f2bf(wa - wb);
  Wb[d * 256 + t] = f2bf(wb);
  W2b[d * 256 + t] = f2bf(w2[d * 256 + t]);
}

// ---------- prep: f32 -> bf16 (vectorized) ----------
__global__ __launch_bounds__(256) void cvt_f32_bf16(
    const float* __restrict__ in, unsigned short* __restrict__ out) {
  size_t i = (size_t)(blockIdx.x * 256 + threadIdx.x) * 4;
  float4 v = *(const float4*)(in + i);
  ushort4 o;
  o.x = f2bf(v.x); o.y = f2bf(v.y); o.z = f2bf(v.z); o.w = f2bf(v.w);
  *(ushort4*)(out + i) = o;
}

// ---------- prep: pack b coords (//16, 7 bits each) ----------
__global__ __launch_bounds__(256) void pack_coords(
    const int* __restrict__ cb, int* __restrict__ cbp) {
  int i = blockIdx.x * 256 + threadIdx.x;  // [0, NPTS)
  int x = cb[(size_t)i * 3 + 0] >> 4;
  int y = cb[(size_t)i * 3 + 1] >> 4;
  int z = cb[(size_t)i * 3 + 2] >> 4;
  cbp[i] = x | (y << 7) | (z << 14);
}

// ---------- GEMM: C[M,256] = A[M,256](bf16) x W[256,256]^T(bf16) ----------
// 128x128 block tile, BK=64, 4 waves each 64x64 (4x4 of 16x16x32 MFMA)
#define LDT 72  // padded LDS row stride (elems)
__global__ __launch_bounds__(256) void gemm_bf16(
    const short* __restrict__ A, const short* __restrict__ W,
    float* __restrict__ Cf, unsigned short* __restrict__ Cb,
    const float* __restrict__ bias, float bias_scale,
    int c_stride, int c_coloff) {
  __shared__ __attribute__((aligned(16))) short As[128 * LDT];
  __shared__ __attribute__((aligned(16))) short Bs[128 * LDT];
  const int tid = threadIdx.x;
  const int row0 = blockIdx.x * 128;
  const int col0 = blockIdx.y * 128;
  const int w = tid >> 6, lane = tid & 63;
  const int wm = (w & 1) * 64, wn = (w >> 1) * 64;
  f32x4_t acc[4][4] = {};
  for (int k0 = 0; k0 < 256; k0 += 64) {
#pragma unroll
    for (int i = 0; i < 4; i++) {
      int c = tid + 256 * i;
      int r = c >> 3, kc = (c & 7) * 8;
      short8_t va = *(const short8_t*)(A + (size_t)(row0 + r) * 256 + k0 + kc);
      *(short8_t*)(As + r * LDT + kc) = va;
      short8_t vb = *(const short8_t*)(W + (size_t)(col0 + r) * 256 + k0 + kc);
      *(short8_t*)(Bs + r * LDT + kc) = vb;
    }
    __syncthreads();
#pragma unroll
    for (int kk = 0; kk < 64; kk += 32) {
      const int kof = kk + (lane >> 4) * 8;
      bf16x8_t af[4], bfr[4];
#pragma unroll
      for (int i = 0; i < 4; i++) {
        af[i] = __builtin_bit_cast(bf16x8_t,
            *(const short8_t*)(As + (wm + i * 16 + (lane & 15)) * LDT + kof));
        bfr[i] = __builtin_bit_cast(bf16x8_t,
            *(const short8_t*)(Bs + (wn + i * 16 + (lane & 15)) * LDT + kof));
      }
#pragma unroll
      for (int i = 0; i < 4; i++)
#pragma unroll
        for (int j = 0; j < 4; j++)
          acc[i][j] = __builtin_amdgcn_mfma_f32_16x16x32_bf16(
              af[i], bfr[j], acc[i][j], 0, 0, 0);
    }
    __syncthreads();
  }
#pragma unroll
  for (int i = 0; i < 4; i++) {
    int row = row0 + wm + i * 16 + ((lane >> 4) * 4);
#pragma unroll
    for (int j = 0; j < 4; j++) {
      int col = col0 + wn + j * 16 + (lane & 15);
      float bv = bias ? bias[col] * bias_scale : 0.f;
#pragma unroll
      for (int r = 0; r < 4; r++) {
        float v = acc[i][j][r] + bv;
        size_t off = (size_t)(row + r) * c_stride + c_coloff + col;
        if (Cf) Cf[off] = v;
        else Cb[off] = f2bf(v);
      }
    }
  }
}

// ---------- top-k slice scan ----------
// grid (NA/256, KSLICES, NBATCH); thread = one a-point; scans 1024 b-points
__global__ __launch_bounds__(256) void topk_slice(
    const int* __restrict__ coords_a, const int* __restrict__ cbp,
    unsigned* __restrict__ part) {
  const int batch = blockIdx.z;
  const int slice = blockIdx.y;
  const int n = blockIdx.x * 256 + threadIdx.x;
  const int g = (batch << 13) + n;
  const int ax = coords_a[(size_t)g * 3 + 0] >> 4;
  const int ay = coords_a[(size_t)g * 3 + 1] >> 4;
  const int az = coords_a[(size_t)g * 3 + 2] >> 4;
  const int* __restrict__ cb = cbp + (batch << 13) + slice * SLICE_LEN;
  const int jbase = slice * SLICE_LEN;
  unsigned keys[8];
#pragma unroll
  for (int s = 0; s < 8; s++) keys[s] = 0xFFFFFFFFu;
  unsigned mx = 0xFFFFFFFFu;
  for (int j = 0; j < SLICE_LEN; j++) {
    const int pb = cb[j];  // wave-uniform -> s_load
    const int bx = pb & 127, by = (pb >> 7) & 127, bz = (pb >> 14) & 127;
    const int dx = ax - bx, dy = ay - by, dz = az - bz;
    const unsigned d2 = (unsigned)(dx * dx + dy * dy + dz * dz);
    const unsigned key = (d2 << 13) | (unsigned)(jbase + j);
    if (key < mx) {
      bool done = false;
#pragma unroll
      for (int s = 0; s < 8; s++) {
        bool hit = (!done) && (keys[s] == mx);
        if (hit) { keys[s] = key; done = true; }
      }
      mx = keys[0];
#pragma unroll
      for (int s = 1; s < 8; s++) mx = keys[s] > mx ? keys[s] : mx;
    }
  }
  unsigned* o = part + (size_t)g * 64 + slice * 8;
#pragma unroll
  for (int s = 0; s < 8; s++) o[s] = keys[s];
}

// ---------- merge 64 -> 8, emit idx + dw ----------
__global__ __launch_bounds__(256) void topk_merge(
    const unsigned* __restrict__ part, int* __restrict__ idxb,
    float* __restrict__ dwb) {
  const int g = blockIdx.x * 256 + threadIdx.x;  // [0, NPTS)
  const unsigned* p = part + (size_t)g * 64;
  unsigned keys[8];
#pragma unroll
  for (int s = 0; s < 8; s++) keys[s] = 0xFFFFFFFFu;
  unsigned mx = 0xFFFFFFFFu;
  for (int i = 0; i < 64; i++) {
    unsigned key = p[i];
    if (key < mx) {
      bool done = false;
#pragma unroll
      for (int s = 0; s < 8; s++) {
        bool hit = (!done) && (keys[s] == mx);
        if (hit) { keys[s] = key; done = true; }
      }
      mx = keys[0];
#pragma unroll
      for (int s = 1; s < 8; s++) mx = keys[s] > mx ? keys[s] : mx;
    }
  }
#pragma unroll
  for (int k = 0; k < 8; k++) {
    unsigned key = keys[k];
    int j = (int)(key & 8191u);
    float dist = sqrtf((float)(key >> 13)) * (1.0f / 128.0f);
    float w = 0.5f - fminf(dist, 0.5f);
    idxb[(size_t)g * 8 + k] = j;
    dwb[(size_t)g * 8 + k] = w;
  }
}

// ---------- fuse: hsum = sum_k relu(Pa + Pb[idx_k]) * dw_k ; copy a row ----------
__global__ __launch_bounds__(256) void fuse_kernel(
    const unsigned short* __restrict__ Pa, const unsigned short* __restrict__ Pb,
    const int* __restrict__ idxb, const float* __restrict__ dwb,
    const float* __restrict__ a_feats, unsigned short* __restrict__ H,
    float* __restrict__ outp) {
  const int g = blockIdx.x * 4 + (threadIdx.x >> 6);
  const int lane = threadIdx.x & 63;
  const int batch = g >> 13;
  const size_t fo = (size_t)g * 256 + lane * 4;
  ushort4 pav = *(const ushort4*)(Pa + fo);
  const float pa0 = bf2f(pav.x), pa1 = bf2f(pav.y), pa2 = bf2f(pav.z),
              pa3 = bf2f(pav.w);
  float h0 = 0.f, h1 = 0.f, h2 = 0.f, h3 = 0.f;
  const size_t bbase = (size_t)(batch << 13) * 256;
#pragma unroll
  for (int k = 0; k < 8; k++) {
    const int j = idxb[(size_t)g * 8 + k];
    const float w = dwb[(size_t)g * 8 + k];
    const ushort4 pbv =
        *(const ushort4*)(Pb + bbase + (size_t)j * 256 + lane * 4);
    h0 += fmaxf(pa0 + bf2f(pbv.x), 0.f) * w;
    h1 += fmaxf(pa1 + bf2f(pbv.y), 0.f) * w;
    h2 += fmaxf(pa2 + bf2f(pbv.z), 0.f) * w;
    h3 += fmaxf(pa3 + bf2f(pbv.w), 0.f) * w;
  }
  ushort4 hv;
  hv.x = f2bf(h0); hv.y = f2bf(h1); hv.z = f2bf(h2); hv.w = f2bf(h3);
  *(ushort4*)(H + fo) = hv;
  float4 av = *(const float4*)(a_feats + fo);
  *(float4*)(outp + (size_t)g * 512 + lane * 4) = av;
}

// ---------- launch ----------
extern "C" void kernel_launch(void* const* d_in, const int* in_sizes, int n_in,
                              void* d_out, int out_size, void* d_ws,
                              size_t ws_size, hipStream_t stream) {
  const float* a_feats = (const float*)d_in[0];
  const float* b_feats = (const float*)d_in[1];
  const int* coords_a = (const int*)d_in[2];
  const int* coords_b = (const int*)d_in[3];
  const float* w1 = (const float*)d_in[4];
  const float* b1 = (const float*)d_in[5];
  const float* w2 = (const float*)d_in[6];
  const float* b2 = (const float*)d_in[7];
  float* outp = (float*)d_out;

  char* p = (char*)d_ws;
  unsigned short* Ab = (unsigned short*)p; p += (size_t)NPTS * DIM * 2;   // 16MB
  unsigned short* Bb = (unsigned short*)p; p += (size_t)NPTS * DIM * 2;   // 16MB
  unsigned short* Pa = (unsigned short*)p; p += (size_t)NPTS * DIM * 2;   // 16MB
  unsigned short* Pb = (unsigned short*)p; p += (size_t)NPTS * DIM * 2;   // 16MB
  unsigned short* Hb = (unsigned short*)p; p += (size_t)NPTS * DIM * 2;   // 16MB
  unsigned* part = (unsigned*)p; p += (size_t)NPTS * 64 * 4;              // 8MB
  int* idxb = (int*)p; p += (size_t)NPTS * 8 * 4;                         // 1MB
  float* dwb = (float*)p; p += (size_t)NPTS * 8 * 4;                      // 1MB
  int* cbp = (int*)p; p += (size_t)NPTS * 4;                              // 128KB
  unsigned short* Wdiff = (unsigned short*)p; p += 256 * 256 * 2;
  unsigned short* Wb16 = (unsigned short*)p; p += 256 * 256 * 2;
  unsigned short* W2b = (unsigned short*)p; p += 256 * 256 * 2;

  prep_weights<<<256, 256, 0, stream>>>(w1, w2, Wdiff, Wb16, W2b);
  cvt_f32_bf16<<<NPTS * DIM / 1024, 256, 0, stream>>>(a_feats, Ab);
  cvt_f32_bf16<<<NPTS * DIM / 1024, 256, 0, stream>>>(b_feats, Bb);
  pack_coords<<<NPTS / 256, 256, 0, stream>>>(coords_b, cbp);

  // Pa = A @ Wb^T + b1 (bf16 out) ; Pb = B @ Wdiff^T (bf16 out)
  gemm_bf16<<<dim3(NPTS / 128, 2), 256, 0, stream>>>(
      (const short*)Ab, (const short*)Wb16, nullptr, Pa, b1, 1.0f, 256, 0);
  gemm_bf16<<<dim3(NPTS / 128, 2), 256, 0, stream>>>(
      (const short*)Bb, (const short*)Wdiff, nullptr, Pb, nullptr, 0.0f, 256, 0);

  topk_slice<<<dim3(NA / 256, KSLICES, NBATCH), 256, 0, stream>>>(coords_a, cbp,
                                                                  part);
  topk_merge<<<NPTS / 256, 256, 0, stream>>>(part, idxb, dwb);

  fuse_kernel<<<NPTS / 4, 256, 0, stream>>>(Pa, Pb, idxb, dwb, a_feats, Hb,
                                            outp);

  // out[:, :, 256:512] = H @ w2^T + 8*b2
  gemm_bf16<<<dim3(NPTS / 128, 2), 256, 0, stream>>>(
      (const short*)Hb, (const short*)W2b, outp, nullptr, b2, 8.0f, 512, 256);
}

// Round 2
// 416.577 us; speedup vs baseline: 1.5324x; 1.5324x over previous
//
#include <hip/hip_runtime.h>
#include <math.h>

// ---------- types ----------
typedef short short8_t __attribute__((ext_vector_type(8)));
typedef __bf16 bf16x8_t __attribute__((ext_vector_type(8)));
typedef float f32x4_t __attribute__((ext_vector_type(4)));

__device__ __forceinline__ float bf2f(unsigned short u) {
  unsigned v = ((unsigned)u) << 16;
  return __builtin_bit_cast(float, v);
}
__device__ __forceinline__ unsigned short f2bf(float f) {
  unsigned x = __builtin_bit_cast(unsigned, f);
  x += 0x7fffu + ((x >> 16) & 1u);
  return (unsigned short)(x >> 16);
}

// ---------- constants ----------
// B=4, Na=Nb=8192, D=256, TOPK=8, FULL_SCALE=128, R=0.5
#define NA 8192
#define NB 8192
#define NBATCH 4
#define DIM 256
#define NPTS (NBATCH * NA)        // 32768
#define NSLICE 4
#define SLICE_LEN (NB / NSLICE)   // 2048

// ---------- prep: weights to bf16 ----------
__global__ __launch_bounds__(256) void prep_weights(
    const float* __restrict__ w1, const float* __restrict__ w2,
    unsigned short* __restrict__ Wdiff, unsigned short* __restrict__ Wb,
    unsigned short* __restrict__ W2b) {
  int d = blockIdx.x, t = threadIdx.x;
  float wa = w1[d * 512 + t];
  float wb = w1[d * 512 + 256 + t];
  Wdiff[d * 256 + t] = f2bf(wa - wb);
  Wb[d * 256 + t] = f2bf(wb);
  W2b[d * 256 + t] = f2bf(w2[d * 256 + t]);
}

// ---------- prep: f32 -> bf16 (vectorized) ----------
__global__ __launch_bounds__(256) void cvt_f32_bf16(
    const float* __restrict__ in, unsigned short* __restrict__ out) {
  size_t i = (size_t)(blockIdx.x * 256 + threadIdx.x) * 4;
  float4 v = *(const float4*)(in + i);
  ushort4 o;
  o.x = f2bf(v.x); o.y = f2bf(v.y); o.z = f2bf(v.z); o.w = f2bf(v.w);
  *(ushort4*)(out + i) = o;
}

// ---------- prep: pack b coords (//16, 7 bits each) ----------
__global__ __launch_bounds__(256) void pack_coords(
    const int* __restrict__ cb, int* __restrict__ cbp) {
  int i = blockIdx.x * 256 + threadIdx.x;  // [0, NPTS)
  int x = (cb[(size_t)i * 3 + 0] >> 4) & 127;
  int y = (cb[(size_t)i * 3 + 1] >> 4) & 127;
  int z = (cb[(size_t)i * 3 + 2] >> 4) & 127;
  cbp[i] = x | (y << 7) | (z << 14);
}

// ---------- GEMM: C[M,256] = A[M,256](bf16) x W[256,256]^T(bf16) ----------
#define LDT 72  // padded LDS row stride (elems)
__global__ __launch_bounds__(256) void gemm_bf16(
    const short* __restrict__ A, const short* __restrict__ W,
    float* __restrict__ Cf, unsigned short* __restrict__ Cb,
    const float* __restrict__ bias, float bias_scale,
    int c_stride, int c_coloff) {
  __shared__ __attribute__((aligned(16))) short As[128 * LDT];
  __shared__ __attribute__((aligned(16))) short Bs[128 * LDT];
  const int tid = threadIdx.x;
  const int row0 = blockIdx.x * 128;
  const int col0 = blockIdx.y * 128;
  const int w = tid >> 6, lane = tid & 63;
  const int wm = (w & 1) * 64, wn = (w >> 1) * 64;
  f32x4_t acc[4][4] = {};
  for (int k0 = 0; k0 < 256; k0 += 64) {
#pragma unroll
    for (int i = 0; i < 4; i++) {
      int c = tid + 256 * i;
      int r = c >> 3, kc = (c & 7) * 8;
      short8_t va = *(const short8_t*)(A + (size_t)(row0 + r) * 256 + k0 + kc);
      *(short8_t*)(As + r * LDT + kc) = va;
      short8_t vb = *(const short8_t*)(W + (size_t)(col0 + r) * 256 + k0 + kc);
      *(short8_t*)(Bs + r * LDT + kc) = vb;
    }
    __syncthreads();
#pragma unroll
    for (int kk = 0; kk < 64; kk += 32) {
      const int kof = kk + (lane >> 4) * 8;
      bf16x8_t af[4], bfr[4];
#pragma unroll
      for (int i = 0; i < 4; i++) {
        af[i] = __builtin_bit_cast(bf16x8_t,
            *(const short8_t*)(As + (wm + i * 16 + (lane & 15)) * LDT + kof));
        bfr[i] = __builtin_bit_cast(bf16x8_t,
            *(const short8_t*)(Bs + (wn + i * 16 + (lane & 15)) * LDT + kof));
      }
#pragma unroll
      for (int i = 0; i < 4; i++)
#pragma unroll
        for (int j = 0; j < 4; j++)
          acc[i][j] = __builtin_amdgcn_mfma_f32_16x16x32_bf16(
              af[i], bfr[j], acc[i][j], 0, 0, 0);
    }
    __syncthreads();
  }
#pragma unroll
  for (int i = 0; i < 4; i++) {
    int row = row0 + wm + i * 16 + ((lane >> 4) * 4);
#pragma unroll
    for (int j = 0; j < 4; j++) {
      int col = col0 + wn + j * 16 + (lane & 15);
      float bv = bias ? bias[col] * bias_scale : 0.f;
#pragma unroll
      for (int r = 0; r < 4; r++) {
        float v = acc[i][j][r] + bv;
        size_t off = (size_t)(row + r) * c_stride + c_coloff + col;
        if (Cf) Cf[off] = v;
        else Cb[off] = f2bf(v);
      }
    }
  }
}

// ---------- top-k slice scan (LDS-staged, mad24, cheap insert) ----------
// grid (NA/256, NSLICE, NBATCH); thread = one a-point; scans SLICE_LEN b-points
// Partials layout (coalesced both ways): part[(slice*8+s)*NPTS + g]
__global__ __launch_bounds__(256) void topk_slice(
    const int* __restrict__ coords_a, const int* __restrict__ cbp,
    unsigned* __restrict__ part) {
  __shared__ int4 sc[SLICE_LEN / 4];  // 8 KB
  const int batch = blockIdx.z;
  const int slice = blockIdx.y;
  const int n = blockIdx.x * 256 + threadIdx.x;
  const int g = (batch << 13) + n;
  const int4* src = (const int4*)(cbp + (batch << 13) + slice * SLICE_LEN);
  for (int i = threadIdx.x; i < SLICE_LEN / 4; i += 256) sc[i] = src[i];
  const int ax = (coords_a[(size_t)g * 3 + 0] >> 4) & 127;
  const int ay = (coords_a[(size_t)g * 3 + 1] >> 4) & 127;
  const int az = (coords_a[(size_t)g * 3 + 2] >> 4) & 127;
  __syncthreads();
  // keys hold (d2<<13)|j — all real keys are unique (distinct j) and
  // < 0xFFFFFFF8, so distinct sentinels keep the "exactly one == mx"
  // invariant without a done-chain.
  unsigned keys[8];
#pragma unroll
  for (int s = 0; s < 8; s++) keys[s] = 0xFFFFFFF8u + s;
  unsigned mx = 0xFFFFFFFFu;
  const int jbase = slice * SLICE_LEN;
  int4 cur = sc[0];
  for (int c = 0; c < SLICE_LEN / 4; c++) {
    int4 nxt = sc[(c + 1 < SLICE_LEN / 4) ? (c + 1) : c];
    const int pv[4] = {cur.x, cur.y, cur.z, cur.w};
#pragma unroll
    for (int t = 0; t < 4; t++) {
      const int v = pv[t];
      const int bx = v & 127, by = (v >> 7) & 127, bz = (v >> 14) & 127;
      const int dx = ax - bx, dy = ay - by, dz = az - bz;
      const unsigned d2 = (unsigned)(dx * dx + dy * dy + dz * dz);
      const unsigned key = (d2 << 13) | (unsigned)(jbase + c * 4 + t);
      if (key < mx) {
#pragma unroll
        for (int s = 0; s < 8; s++) keys[s] = (keys[s] == mx) ? key : keys[s];
        unsigned m = keys[0];
#pragma unroll
        for (int s = 1; s < 8; s++) m = keys[s] > m ? keys[s] : m;
        mx = m;
      }
    }
    cur = nxt;
  }
#pragma unroll
  for (int s = 0; s < 8; s++) part[(size_t)(slice * 8 + s) * NPTS + g] = keys[s];
}

// ---------- merge NSLICE*8 -> 8, emit idx + dw ----------
__global__ __launch_bounds__(256) void topk_merge(
    const unsigned* __restrict__ part, int* __restrict__ idxb,
    float* __restrict__ dwb) {
  const int g = blockIdx.x * 256 + threadIdx.x;  // [0, NPTS)
  unsigned keys[8];
#pragma unroll
  for (int s = 0; s < 8; s++) keys[s] = 0xFFFFFFF8u + s;
  unsigned mx = 0xFFFFFFFFu;
  for (int i = 0; i < NSLICE * 8; i++) {
    unsigned key = part[(size_t)i * NPTS + g];  // coalesced
    if (key < mx) {
#pragma unroll
      for (int s = 0; s < 8; s++) keys[s] = (keys[s] == mx) ? key : keys[s];
      unsigned m = keys[0];
#pragma unroll
      for (int s = 1; s < 8; s++) m = keys[s] > m ? keys[s] : m;
      mx = m;
    }
  }
#pragma unroll
  for (int k = 0; k < 8; k++) {
    unsigned key = keys[k];
    int j = (int)(key & 8191u);
    float dist = sqrtf((float)(key >> 13)) * (1.0f / 128.0f);
    float w = 0.5f - fminf(dist, 0.5f);
    idxb[(size_t)g * 8 + k] = j;
    dwb[(size_t)g * 8 + k] = w;
  }
}

// ---------- fuse: hsum = sum_k relu(Pa + Pb[idx_k]) * dw_k ; copy a row ----------
__global__ __launch_bounds__(256) void fuse_kernel(
    const unsigned short* __restrict__ Pa, const unsigned short* __restrict__ Pb,
    const int* __restrict__ idxb, const float* __restrict__ dwb,
    const float* __restrict__ a_feats, unsigned short* __restrict__ H,
    float* __restrict__ outp) {
  const int g = blockIdx.x * 4 + (threadIdx.x >> 6);
  const int lane = threadIdx.x & 63;
  const int batch = g >> 13;
  const size_t fo = (size_t)g * 256 + lane * 4;
  ushort4 pav = *(const ushort4*)(Pa + fo);
  const float pa0 = bf2f(pav.x), pa1 = bf2f(pav.y), pa2 = bf2f(pav.z),
              pa3 = bf2f(pav.w);
  float h0 = 0.f, h1 = 0.f, h2 = 0.f, h3 = 0.f;
  const size_t bbase = (size_t)(batch << 13) * 256;
#pragma unroll
  for (int k = 0; k < 8; k++) {
    const int j = idxb[(size_t)g * 8 + k];
    const float w = dwb[(size_t)g * 8 + k];
    const ushort4 pbv =
        *(const ushort4*)(Pb + bbase + (size_t)j * 256 + lane * 4);
    h0 += fmaxf(pa0 + bf2f(pbv.x), 0.f) * w;
    h1 += fmaxf(pa1 + bf2f(pbv.y), 0.f) * w;
    h2 += fmaxf(pa2 + bf2f(pbv.z), 0.f) * w;
    h3 += fmaxf(pa3 + bf2f(pbv.w), 0.f) * w;
  }
  ushort4 hv;
  hv.x = f2bf(h0); hv.y = f2bf(h1); hv.z = f2bf(h2); hv.w = f2bf(h3);
  *(ushort4*)(H + fo) = hv;
  float4 av = *(const float4*)(a_feats + fo);
  *(float4*)(outp + (size_t)g * 512 + lane * 4) = av;
}

// ---------- launch ----------
extern "C" void kernel_launch(void* const* d_in, const int* in_sizes, int n_in,
                              void* d_out, int out_size, void* d_ws,
                              size_t ws_size, hipStream_t stream) {
  const float* a_feats = (const float*)d_in[0];
  const float* b_feats = (const float*)d_in[1];
  const int* coords_a = (const int*)d_in[2];
  const int* coords_b = (const int*)d_in[3];
  const float* w1 = (const float*)d_in[4];
  const float* b1 = (const float*)d_in[5];
  const float* w2 = (const float*)d_in[6];
  const float* b2 = (const float*)d_in[7];
  float* outp = (float*)d_out;

  char* p = (char*)d_ws;
  unsigned short* Ab = (unsigned short*)p; p += (size_t)NPTS * DIM * 2;   // 16MB
  unsigned short* Bb = (unsigned short*)p; p += (size_t)NPTS * DIM * 2;   // 16MB
  unsigned short* Pa = (unsigned short*)p; p += (size_t)NPTS * DIM * 2;   // 16MB
  unsigned short* Pb = (unsigned short*)p; p += (size_t)NPTS * DIM * 2;   // 16MB
  unsigned short* Hb = (unsigned short*)p; p += (size_t)NPTS * DIM * 2;   // 16MB
  unsigned* part = (unsigned*)p; p += (size_t)NPTS * (NSLICE * 8) * 4;    // 4MB
  int* idxb = (int*)p; p += (size_t)NPTS * 8 * 4;                         // 1MB
  float* dwb = (float*)p; p += (size_t)NPTS * 8 * 4;                      // 1MB
  int* cbp = (int*)p; p += (size_t)NPTS * 4;                              // 128KB
  unsigned short* Wdiff = (unsigned short*)p; p += 256 * 256 * 2;
  unsigned short* Wb16 = (unsigned short*)p; p += 256 * 256 * 2;
  unsigned short* W2b = (unsigned short*)p; p += 256 * 256 * 2;

  prep_weights<<<256, 256, 0, stream>>>(w1, w2, Wdiff, Wb16, W2b);
  cvt_f32_bf16<<<NPTS * DIM / 1024, 256, 0, stream>>>(a_feats, Ab);
  cvt_f32_bf16<<<NPTS * DIM / 1024, 256, 0, stream>>>(b_feats, Bb);
  pack_coords<<<NPTS / 256, 256, 0, stream>>>(coords_b, cbp);

  // Pa = A @ Wb^T + b1 (bf16 out) ; Pb = B @ Wdiff^T (bf16 out)
  gemm_bf16<<<dim3(NPTS / 128, 2), 256, 0, stream>>>(
      (const short*)Ab, (const short*)Wb16, nullptr, Pa, b1, 1.0f, 256, 0);
  gemm_bf16<<<dim3(NPTS / 128, 2), 256, 0, stream>>>(
      (const short*)Bb, (const short*)Wdiff, nullptr, Pb, nullptr, 0.0f, 256, 0);

  topk_slice<<<dim3(NA / 256, NSLICE, NBATCH), 256, 0, stream>>>(coords_a, cbp,
                                                                 part);
  topk_merge<<<NPTS / 256, 256, 0, stream>>>(part, idxb, dwb);

  fuse_kernel<<<NPTS / 4, 256, 0, stream>>>(Pa, Pb, idxb, dwb, a_feats, Hb,
                                            outp);

  // out[:, :, 256:512] = H @ w2^T + 8*b2
  gemm_bf16<<<dim3(NPTS / 128, 2), 256, 0, stream>>>(
      (const short*)Hb, (const short*)W2b, outp, nullptr, b2, 8.0f, 512, 256);
}

// Round 4
// 333.816 us; speedup vs baseline: 1.9124x; 1.2479x over previous
//
#include <hip/hip_runtime.h>
#include <math.h>

// ---------- types ----------
typedef short short8_t __attribute__((ext_vector_type(8)));
typedef __bf16 bf16x8_t __attribute__((ext_vector_type(8)));
typedef float f32x4_t __attribute__((ext_vector_type(4)));

__device__ __forceinline__ float bf2f(unsigned short u) {
  unsigned v = ((unsigned)u) << 16;
  return __builtin_bit_cast(float, v);
}
__device__ __forceinline__ unsigned short f2bf(float f) {
  unsigned x = __builtin_bit_cast(unsigned, f);
  x += 0x7fffu + ((x >> 16) & 1u);
  return (unsigned short)(x >> 16);
}

// ---------- constants ----------
#define NA 8192
#define NB 8192
#define NBATCH 4
#define DIM 256
#define NPTS (NBATCH * NA)  // 32768
#define NCELL 2048          // 4 batches x 8x8x8 cells (cell edge 16)

// Branchless sorted top-8 insert: k[0..7] ascending, ~15 VALU ops.
// Correct for any x: if x >= k[7] the bubble pass is the identity.
__device__ __forceinline__ void kins(unsigned k[8], unsigned x) {
  unsigned c = x < k[7] ? x : k[7];
#pragma unroll
  for (int i = 6; i >= 0; i--) {
    unsigned hi = k[i] > c ? k[i] : c;
    c = k[i] < c ? k[i] : c;
    k[i + 1] = hi;
  }
  k[0] = c;
}

// ---------- prep: weights to bf16 ----------
__global__ __launch_bounds__(256) void prep_weights(
    const float* __restrict__ w1, const float* __restrict__ w2,
    unsigned short* __restrict__ Wdiff, unsigned short* __restrict__ Wb,
    unsigned short* __restrict__ W2b) {
  int d = blockIdx.x, t = threadIdx.x;
  float wa = w1[d * 512 + t];
  float wb = w1[d * 512 + 256 + t];
  Wdiff[d * 256 + t] = f2bf(wa - wb);
  Wb[d * 256 + t] = f2bf(wb);
  W2b[d * 256 + t] = f2bf(w2[d * 256 + t]);
}

// ---------- prep: f32 -> bf16 ----------
__global__ __launch_bounds__(256) void cvt_f32_bf16(
    const float* __restrict__ in, unsigned short* __restrict__ out) {
  size_t i = (size_t)(blockIdx.x * 256 + threadIdx.x) * 4;
  float4 v = *(const float4*)(in + i);
  ushort4 o;
  o.x = f2bf(v.x); o.y = f2bf(v.y); o.z = f2bf(v.z); o.w = f2bf(v.w);
  *(ushort4*)(out + i) = o;
}

// ---------- binning: zero counters ----------
__global__ __launch_bounds__(256) void zero_counts(
    unsigned* __restrict__ bcnt, unsigned* __restrict__ acnt,
    unsigned* __restrict__ failcnt) {
  int i = blockIdx.x * 256 + threadIdx.x;  // grid 8 -> 2048
  bcnt[i] = 0;
  acnt[i] = 0;
  if (i == 0) *failcnt = 0;
}

// ---------- binning: pack coords (//16, 7b each) + histogram cells ----------
__global__ __launch_bounds__(256) void pack_count(
    const int* __restrict__ coords, unsigned* __restrict__ pk,
    unsigned* __restrict__ cnt) {
  int i = blockIdx.x * 256 + threadIdx.x;  // [0, NPTS)
  int x = (coords[(size_t)i * 3 + 0] >> 4) & 127;
  int y = (coords[(size_t)i * 3 + 1] >> 4) & 127;
  int z = (coords[(size_t)i * 3 + 2] >> 4) & 127;
  pk[i] = (unsigned)(x | (y << 7) | (z << 14));
  int cid = ((i >> 13) << 9) | ((x >> 4) << 6) | ((y >> 4) << 3) | (z >> 4);
  atomicAdd(cnt + cid, 1u);
}

// ---------- binning: exclusive scan of both 2048-entry tables ----------
__global__ __launch_bounds__(256) void scan_cells(
    const unsigned* __restrict__ bcnt, const unsigned* __restrict__ acnt,
    unsigned* __restrict__ boff, unsigned* __restrict__ aoff,
    unsigned* __restrict__ bcur, unsigned* __restrict__ acur) {
  __shared__ unsigned p[256];
  const int t = threadIdx.x;
  for (int tab = 0; tab < 2; tab++) {
    const unsigned* cnt = tab ? acnt : bcnt;
    unsigned* off = tab ? aoff : boff;
    unsigned* cur = tab ? acur : bcur;
    unsigned loc[8], sum = 0;
#pragma unroll
    for (int k = 0; k < 8; k++) { loc[k] = sum; sum += cnt[t * 8 + k]; }
    p[t] = sum;
    __syncthreads();
    for (int d = 1; d < 256; d <<= 1) {
      unsigned v = (t >= d) ? p[t - d] : 0u;
      __syncthreads();
      p[t] += v;
      __syncthreads();
    }
    unsigned base = (t == 0) ? 0u : p[t - 1];
#pragma unroll
    for (int k = 0; k < 8; k++) {
      unsigned o = base + loc[k];
      off[t * 8 + k] = o;
      cur[t * 8 + k] = o;
    }
    if (t == 255) off[2048] = base + sum;
    __syncthreads();
  }
}

// ---------- binning: scatter points into cell-sorted {coord, idx} pairs ----------
__global__ __launch_bounds__(256) void scatter_pts(
    const unsigned* __restrict__ pk, unsigned* __restrict__ cur,
    uint2* __restrict__ out) {
  int i = blockIdx.x * 256 + threadIdx.x;  // [0, NPTS)
  unsigned v = pk[i];
  int cx = (v & 127) >> 4, cy = ((v >> 7) & 127) >> 4, cz = ((v >> 14) & 127) >> 4;
  int cid = ((i >> 13) << 9) | (cx << 6) | (cy << 3) | cz;
  unsigned pos = atomicAdd(cur + cid, 1u);
  out[pos] = make_uint2(v, (unsigned)(i & 8191));
}

// ---------- GEMM: C[M,256] = A[M,256](bf16) x W[256,256]^T(bf16) ----------
#define LDT 72
__global__ __launch_bounds__(256) void gemm_bf16(
    const short* __restrict__ A, const short* __restrict__ W,
    float* __restrict__ Cf, unsigned short* __restrict__ Cb,
    const float* __restrict__ bias, float bias_scale,
    int c_stride, int c_coloff) {
  __shared__ __attribute__((aligned(16))) short As[128 * LDT];
  __shared__ __attribute__((aligned(16))) short Bs[128 * LDT];
  const int tid = threadIdx.x;
  const int row0 = blockIdx.x * 128;
  const int col0 = blockIdx.y * 128;
  const int w = tid >> 6, lane = tid & 63;
  const int wm = (w & 1) * 64, wn = (w >> 1) * 64;
  f32x4_t acc[4][4] = {};
  for (int k0 = 0; k0 < 256; k0 += 64) {
#pragma unroll
    for (int i = 0; i < 4; i++) {
      int c = tid + 256 * i;
      int r = c >> 3, kc = (c & 7) * 8;
      short8_t va = *(const short8_t*)(A + (size_t)(row0 + r) * 256 + k0 + kc);
      *(short8_t*)(As + r * LDT + kc) = va;
      short8_t vb = *(const short8_t*)(W + (size_t)(col0 + r) * 256 + k0 + kc);
      *(short8_t*)(Bs + r * LDT + kc) = vb;
    }
    __syncthreads();
#pragma unroll
    for (int kk = 0; kk < 64; kk += 32) {
      const int kof = kk + (lane >> 4) * 8;
      bf16x8_t af[4], bfr[4];
#pragma unroll
      for (int i = 0; i < 4; i++) {
        af[i] = __builtin_bit_cast(bf16x8_t,
            *(const short8_t*)(As + (wm + i * 16 + (lane & 15)) * LDT + kof));
        bfr[i] = __builtin_bit_cast(bf16x8_t,
            *(const short8_t*)(Bs + (wn + i * 16 + (lane & 15)) * LDT + kof));
      }
#pragma unroll
      for (int i = 0; i < 4; i++)
#pragma unroll
        for (int j = 0; j < 4; j++)
          acc[i][j] = __builtin_amdgcn_mfma_f32_16x16x32_bf16(
              af[i], bfr[j], acc[i][j], 0, 0, 0);
    }
    __syncthreads();
  }
#pragma unroll
  for (int i = 0; i < 4; i++) {
    int row = row0 + wm + i * 16 + ((lane >> 4) * 4);
#pragma unroll
    for (int j = 0; j < 4; j++) {
      int col = col0 + wn + j * 16 + (lane & 15);
      float bv = bias ? bias[col] * bias_scale : 0.f;
#pragma unroll
      for (int r = 0; r < 4; r++) {
        float v = acc[i][j][r] + bv;
        size_t off = (size_t)(row + r) * c_stride + c_coloff + col;
        if (Cf) Cf[off] = v;
        else Cb[off] = f2bf(v);
      }
    }
  }
}

// ---------- primary top-k: one thread per cell-sorted a-point ----------
// Scans the 3x3x3 cell neighborhood directly from global (L1/L2-resident:
// adjacent lanes are same-cell a-points reading the same segments).
// Exact iff 8th-best d2 <= 288 (any point outside the neighborhood has a
// per-dim cell diff >= 2 => |delta| >= 17 => d2 >= 289, and keys embed the
// original index so reference tie-breaking is preserved). Otherwise the
// a-point is appended to faillist for an exact full scan.
__global__ __launch_bounds__(256) void topk_bins(
    const unsigned* __restrict__ boff, const uint2* __restrict__ bcj,
    const uint2* __restrict__ acj, int* __restrict__ idxb,
    float* __restrict__ dwb, unsigned* __restrict__ failcnt,
    unsigned* __restrict__ faillist) {
  const int t = blockIdx.x * 256 + threadIdx.x;  // cell-sorted a index
  const uint2 av = acj[t];
  const int batch = t >> 13;  // batches are contiguous in cell order
  const int ax = av.x & 127, ay = (av.x >> 7) & 127, az = (av.x >> 14) & 127;
  const int cx = ax >> 4, cy = ay >> 4, cz = az >> 4;
  const int xlo = max(cx - 1, 0), xhi = min(cx + 1, 7);
  const int ylo = max(cy - 1, 0), yhi = min(cy + 1, 7);
  const int zlo = max(cz - 1, 0), zhi1 = min(cz + 1, 7) + 1;
  unsigned k[8];
#pragma unroll
  for (int s = 0; s < 8; s++) k[s] = 0xFFFFFFF8u + s;
  for (int nx = xlo; nx <= xhi; nx++) {
    for (int ny = ylo; ny <= yhi; ny++) {
      const int cb = (batch << 9) | (nx << 6) | (ny << 3);
      const int gs = (int)boff[cb + zlo];
      const int ge = (int)boff[cb + zhi1];
      for (int i = gs; i < ge; i++) {
        const uint2 b = bcj[i];
        const int dx = ax - (int)(b.x & 127);
        const int dy = ay - (int)((b.x >> 7) & 127);
        const int dz = az - (int)((b.x >> 14) & 127);
        const unsigned d2 = (unsigned)(__mul24(dx, dx) + __mul24(dy, dy) +
                                       __mul24(dz, dz));
        kins(k, (d2 << 13) | b.y);
      }
    }
  }
  const int g = (batch << 13) | (int)av.y;
#pragma unroll
  for (int s = 0; s < 8; s++) {
    unsigned key = k[s];
    idxb[(size_t)g * 8 + s] = (int)(key & 8191u);
    float dist = sqrtf((float)(key >> 13)) * (1.0f / 128.0f);
    dwb[(size_t)g * 8 + s] = 0.5f - fminf(dist, 0.5f);
  }
  if (k[7] >= (289u << 13)) {  // also catches <8 real candidates (sentinels)
    unsigned fp = atomicAdd(failcnt, 1u);
    faillist[fp] = (unsigned)g;
  }
}

// ---------- fallback: exact full scan, one wave per failed a-point ----------
// Per-lane top-8 over a disjoint 128-point strided slice, then a shfl-XOR
// butterfly allreduce (merged groups are always from disjoint sources, so
// no candidate is ever double-counted).
__global__ __launch_bounds__(256) void topk_fallback(
    const unsigned* __restrict__ failcnt, const unsigned* __restrict__ faillist,
    const uint2* __restrict__ bcj, const unsigned* __restrict__ apk,
    int* __restrict__ idxb, float* __restrict__ dwb) {
  const int wave = (blockIdx.x * 256 + threadIdx.x) >> 6;  // 0..511
  const int lane = threadIdx.x & 63;
  const unsigned nf = *failcnt;
  for (unsigned fi = wave; fi < nf; fi += 512) {
    const unsigned g = faillist[fi];
    const int batch = (int)(g >> 13);
    const unsigned av = apk[g];
    const int ax = av & 127, ay = (av >> 7) & 127, az = (av >> 14) & 127;
    const uint2* pb = bcj + ((size_t)batch << 13);
    unsigned k[8];
#pragma unroll
    for (int s = 0; s < 8; s++) k[s] = 0xFFFFFFF8u + s;
    for (int i = lane; i < NB; i += 64) {
      const uint2 b = pb[i];
      const int dx = ax - (int)(b.x & 127);
      const int dy = ay - (int)((b.x >> 7) & 127);
      const int dz = az - (int)((b.x >> 14) & 127);
      const unsigned d2 = (unsigned)(__mul24(dx, dx) + __mul24(dy, dy) +
                                     __mul24(dz, dz));
      kins(k, (d2 << 13) | b.y);
    }
#pragma unroll
    for (int half = 32; half >= 1; half >>= 1) {
      unsigned o[8];
#pragma unroll
      for (int s = 0; s < 8; s++)
        o[s] = (unsigned)__shfl((int)k[s], lane ^ half, 64);
#pragma unroll
      for (int s = 0; s < 8; s++) kins(k, o[s]);
    }
    if (lane == 0) {
#pragma unroll
      for (int s = 0; s < 8; s++) {
        unsigned key = k[s];
        idxb[(size_t)g * 8 + s] = (int)(key & 8191u);
        float dist = sqrtf((float)(key >> 13)) * (1.0f / 128.0f);
        dwb[(size_t)g * 8 + s] = 0.5f - fminf(dist, 0.5f);
      }
    }
  }
}

// ---------- fuse: hsum = sum_k relu(Pa + Pb[idx_k]) * dw_k ; copy a row ----------
__global__ __launch_bounds__(256) void fuse_kernel(
    const unsigned short* __restrict__ Pa, const unsigned short* __restrict__ Pb,
    const int* __restrict__ idxb, const float* __restrict__ dwb,
    const float* __restrict__ a_feats, unsigned short* __restrict__ H,
    float* __restrict__ outp) {
  const int g = blockIdx.x * 4 + (threadIdx.x >> 6);
  const int lane = threadIdx.x & 63;
  const int batch = g >> 13;
  const size_t fo = (size_t)g * 256 + lane * 4;
  ushort4 pav = *(const ushort4*)(Pa + fo);
  const float pa0 = bf2f(pav.x), pa1 = bf2f(pav.y), pa2 = bf2f(pav.z),
              pa3 = bf2f(pav.w);
  float h0 = 0.f, h1 = 0.f, h2 = 0.f, h3 = 0.f;
  const size_t bbase = (size_t)(batch << 13) * 256;
#pragma unroll
  for (int k = 0; k < 8; k++) {
    const int j = idxb[(size_t)g * 8 + k];
    const float w = dwb[(size_t)g * 8 + k];
    const ushort4 pbv =
        *(const ushort4*)(Pb + bbase + (size_t)j * 256 + lane * 4);
    h0 += fmaxf(pa0 + bf2f(pbv.x), 0.f) * w;
    h1 += fmaxf(pa1 + bf2f(pbv.y), 0.f) * w;
    h2 += fmaxf(pa2 + bf2f(pbv.z), 0.f) * w;
    h3 += fmaxf(pa3 + bf2f(pbv.w), 0.f) * w;
  }
  ushort4 hv;
  hv.x = f2bf(h0); hv.y = f2bf(h1); hv.z = f2bf(h2); hv.w = f2bf(h3);
  *(ushort4*)(H + fo) = hv;
  float4 av = *(const float4*)(a_feats + fo);
  *(float4*)(outp + (size_t)g * 512 + lane * 4) = av;
}

// ---------- launch ----------
extern "C" void kernel_launch(void* const* d_in, const int* in_sizes, int n_in,
                              void* d_out, int out_size, void* d_ws,
                              size_t ws_size, hipStream_t stream) {
  const float* a_feats = (const float*)d_in[0];
  const float* b_feats = (const float*)d_in[1];
  const int* coords_a = (const int*)d_in[2];
  const int* coords_b = (const int*)d_in[3];
  const float* w1 = (const float*)d_in[4];
  const float* b1 = (const float*)d_in[5];
  const float* w2 = (const float*)d_in[6];
  const float* b2 = (const float*)d_in[7];
  float* outp = (float*)d_out;

  char* p = (char*)d_ws;
  auto take = [&](size_t bytes) {
    char* r = p;
    p += (bytes + 255) & ~(size_t)255;
    return r;
  };
  unsigned short* Ab = (unsigned short*)take((size_t)NPTS * DIM * 2);
  unsigned short* Bb = (unsigned short*)take((size_t)NPTS * DIM * 2);
  unsigned short* Pa = (unsigned short*)take((size_t)NPTS * DIM * 2);
  unsigned short* Pb = (unsigned short*)take((size_t)NPTS * DIM * 2);
  unsigned short* Hb = (unsigned short*)take((size_t)NPTS * DIM * 2);
  int* idxb = (int*)take((size_t)NPTS * 8 * 4);
  float* dwb = (float*)take((size_t)NPTS * 8 * 4);
  unsigned* bpk = (unsigned*)take((size_t)NPTS * 4);
  unsigned* apk = (unsigned*)take((size_t)NPTS * 4);
  unsigned* bcnt = (unsigned*)take(NCELL * 4);
  unsigned* acnt = (unsigned*)take(NCELL * 4);
  unsigned* bcur = (unsigned*)take(NCELL * 4);
  unsigned* acur = (unsigned*)take(NCELL * 4);
  unsigned* boff = (unsigned*)take((NCELL + 1) * 4);
  unsigned* aoff = (unsigned*)take((NCELL + 1) * 4);
  uint2* bcj = (uint2*)take((size_t)NPTS * 8);
  uint2* acj = (uint2*)take((size_t)NPTS * 8);
  unsigned* failcnt = (unsigned*)take(256);
  unsigned* faillist = (unsigned*)take((size_t)NPTS * 4);
  unsigned short* Wdiff = (unsigned short*)take(256 * 256 * 2);
  unsigned short* Wb16 = (unsigned short*)take(256 * 256 * 2);
  unsigned short* W2b = (unsigned short*)take(256 * 256 * 2);

  prep_weights<<<256, 256, 0, stream>>>(w1, w2, Wdiff, Wb16, W2b);
  cvt_f32_bf16<<<NPTS * DIM / 1024, 256, 0, stream>>>(a_feats, Ab);
  cvt_f32_bf16<<<NPTS * DIM / 1024, 256, 0, stream>>>(b_feats, Bb);

  zero_counts<<<NCELL / 256, 256, 0, stream>>>(bcnt, acnt, failcnt);
  pack_count<<<NPTS / 256, 256, 0, stream>>>(coords_b, bpk, bcnt);
  pack_count<<<NPTS / 256, 256, 0, stream>>>(coords_a, apk, acnt);
  scan_cells<<<1, 256, 0, stream>>>(bcnt, acnt, boff, aoff, bcur, acur);
  scatter_pts<<<NPTS / 256, 256, 0, stream>>>(bpk, bcur, bcj);
  scatter_pts<<<NPTS / 256, 256, 0, stream>>>(apk, acur, acj);

  // Pa = A @ Wb^T + b1 (bf16 out) ; Pb = B @ Wdiff^T (bf16 out)
  gemm_bf16<<<dim3(NPTS / 128, 2), 256, 0, stream>>>(
      (const short*)Ab, (const short*)Wb16, nullptr, Pa, b1, 1.0f, 256, 0);
  gemm_bf16<<<dim3(NPTS / 128, 2), 256, 0, stream>>>(
      (const short*)Bb, (const short*)Wdiff, nullptr, Pb, nullptr, 0.0f, 256, 0);

  topk_bins<<<NPTS / 256, 256, 0, stream>>>(boff, bcj, acj, idxb, dwb, failcnt,
                                            faillist);
  topk_fallback<<<128, 256, 0, stream>>>(failcnt, faillist, bcj, apk, idxb,
                                         dwb);

  fuse_kernel<<<NPTS / 4, 256, 0, stream>>>(Pa, Pb, idxb, dwb, a_feats, Hb,
                                            outp);

  // out[:, :, 256:512] = H @ w2^T + 8*b2
  gemm_bf16<<<dim3(NPTS / 128, 2), 256, 0, stream>>>(
      (const short*)Hb, (const short*)W2b, outp, nullptr, b2, 8.0f, 512, 256);
}

// Round 5
// 271.237 us; speedup vs baseline: 2.3536x; 1.2307x over previous
//
#include <hip/hip_runtime.h>
#include <math.h>

// ---------- types ----------
typedef short short8_t __attribute__((ext_vector_type(8)));
typedef __bf16 bf16x8_t __attribute__((ext_vector_type(8)));
typedef float f32x4_t __attribute__((ext_vector_type(4)));

__device__ __forceinline__ float bf2f(unsigned short u) {
  unsigned v = ((unsigned)u) << 16;
  return __builtin_bit_cast(float, v);
}
__device__ __forceinline__ unsigned short f2bf(float f) {
  unsigned x = __builtin_bit_cast(unsigned, f);
  x += 0x7fffu + ((x >> 16) & 1u);
  return (unsigned short)(x >> 16);
}

// ---------- constants ----------
#define NA 8192
#define NB 8192
#define NBATCH 4
#define DIM 256
#define NPTS (NBATCH * NA)  // 32768
#define NCELL 2048          // 4 batches x 8x8x8 cells (cell edge 16)
#define SUBL 8              // lanes cooperating per a-point in topk_bins

// Branchless sorted top-8 insert: k[0..7] ascending, ~15 VALU ops.
__device__ __forceinline__ void kins(unsigned k[8], unsigned x) {
  unsigned c = x < k[7] ? x : k[7];
#pragma unroll
  for (int i = 6; i >= 0; i--) {
    unsigned hi = k[i] > c ? k[i] : c;
    c = k[i] < c ? k[i] : c;
    k[i + 1] = hi;
  }
  k[0] = c;
}

// ---------- prep: weights to bf16 ----------
__global__ __launch_bounds__(256) void prep_weights(
    const float* __restrict__ w1, const float* __restrict__ w2,
    unsigned short* __restrict__ Wdiff, unsigned short* __restrict__ Wb,
    unsigned short* __restrict__ W2b) {
  int d = blockIdx.x, t = threadIdx.x;
  float wa = w1[d * 512 + t];
  float wb = w1[d * 512 + 256 + t];
  Wdiff[d * 256 + t] = f2bf(wa - wb);
  Wb[d * 256 + t] = f2bf(wb);
  W2b[d * 256 + t] = f2bf(w2[d * 256 + t]);
}

// ---------- prep: f32 -> bf16 ----------
__global__ __launch_bounds__(256) void cvt_f32_bf16(
    const float* __restrict__ in, unsigned short* __restrict__ out) {
  size_t i = (size_t)(blockIdx.x * 256 + threadIdx.x) * 4;
  float4 v = *(const float4*)(in + i);
  ushort4 o;
  o.x = f2bf(v.x); o.y = f2bf(v.y); o.z = f2bf(v.z); o.w = f2bf(v.w);
  *(ushort4*)(out + i) = o;
}

// ---------- binning: zero counters ----------
__global__ __launch_bounds__(256) void zero_counts(
    unsigned* __restrict__ bcnt, unsigned* __restrict__ acnt,
    unsigned* __restrict__ failcnt) {
  int i = blockIdx.x * 256 + threadIdx.x;  // grid 8 -> 2048
  bcnt[i] = 0;
  acnt[i] = 0;
  if (i == 0) *failcnt = 0;
}

// ---------- binning: pack coords (//16, 7b each) + histogram cells ----------
__global__ __launch_bounds__(256) void pack_count(
    const int* __restrict__ coords, unsigned* __restrict__ pk,
    unsigned* __restrict__ cnt) {
  int i = blockIdx.x * 256 + threadIdx.x;  // [0, NPTS)
  int x = (coords[(size_t)i * 3 + 0] >> 4) & 127;
  int y = (coords[(size_t)i * 3 + 1] >> 4) & 127;
  int z = (coords[(size_t)i * 3 + 2] >> 4) & 127;
  pk[i] = (unsigned)(x | (y << 7) | (z << 14));
  int cid = ((i >> 13) << 9) | ((x >> 4) << 6) | ((y >> 4) << 3) | (z >> 4);
  atomicAdd(cnt + cid, 1u);
}

// ---------- binning: exclusive scan of both 2048-entry tables ----------
__global__ __launch_bounds__(256) void scan_cells(
    const unsigned* __restrict__ bcnt, const unsigned* __restrict__ acnt,
    unsigned* __restrict__ boff, unsigned* __restrict__ aoff,
    unsigned* __restrict__ bcur, unsigned* __restrict__ acur) {
  __shared__ unsigned p[256];
  const int t = threadIdx.x;
  for (int tab = 0; tab < 2; tab++) {
    const unsigned* cnt = tab ? acnt : bcnt;
    unsigned* off = tab ? aoff : boff;
    unsigned* cur = tab ? acur : bcur;
    unsigned loc[8], sum = 0;
#pragma unroll
    for (int k = 0; k < 8; k++) { loc[k] = sum; sum += cnt[t * 8 + k]; }
    p[t] = sum;
    __syncthreads();
    for (int d = 1; d < 256; d <<= 1) {
      unsigned v = (t >= d) ? p[t - d] : 0u;
      __syncthreads();
      p[t] += v;
      __syncthreads();
    }
    unsigned base = (t == 0) ? 0u : p[t - 1];
#pragma unroll
    for (int k = 0; k < 8; k++) {
      unsigned o = base + loc[k];
      off[t * 8 + k] = o;
      cur[t * 8 + k] = o;
    }
    if (t == 255) off[2048] = base + sum;
    __syncthreads();
  }
}

// ---------- binning: scatter points into cell-sorted {coord, idx} pairs ----------
__global__ __launch_bounds__(256) void scatter_pts(
    const unsigned* __restrict__ pk, unsigned* __restrict__ cur,
    uint2* __restrict__ out) {
  int i = blockIdx.x * 256 + threadIdx.x;  // [0, NPTS)
  unsigned v = pk[i];
  int cx = (v & 127) >> 4, cy = ((v >> 7) & 127) >> 4, cz = ((v >> 14) & 127) >> 4;
  int cid = ((i >> 13) << 9) | (cx << 6) | (cy << 3) | cz;
  unsigned pos = atomicAdd(cur + cid, 1u);
  out[pos] = make_uint2(v, (unsigned)(i & 8191));
}

// ---------- GEMM: C[M,256] = A[M,256](bf16) x W[256,256]^T(bf16) ----------
#define LDT 72
__global__ __launch_bounds__(256) void gemm_bf16(
    const short* __restrict__ A, const short* __restrict__ W,
    float* __restrict__ Cf, unsigned short* __restrict__ Cb,
    const float* __restrict__ bias, float bias_scale,
    int c_stride, int c_coloff) {
  __shared__ __attribute__((aligned(16))) short As[128 * LDT];
  __shared__ __attribute__((aligned(16))) short Bs[128 * LDT];
  const int tid = threadIdx.x;
  const int row0 = blockIdx.x * 128;
  const int col0 = blockIdx.y * 128;
  const int w = tid >> 6, lane = tid & 63;
  const int wm = (w & 1) * 64, wn = (w >> 1) * 64;
  f32x4_t acc[4][4] = {};
  for (int k0 = 0; k0 < 256; k0 += 64) {
#pragma unroll
    for (int i = 0; i < 4; i++) {
      int c = tid + 256 * i;
      int r = c >> 3, kc = (c & 7) * 8;
      short8_t va = *(const short8_t*)(A + (size_t)(row0 + r) * 256 + k0 + kc);
      *(short8_t*)(As + r * LDT + kc) = va;
      short8_t vb = *(const short8_t*)(W + (size_t)(col0 + r) * 256 + k0 + kc);
      *(short8_t*)(Bs + r * LDT + kc) = vb;
    }
    __syncthreads();
#pragma unroll
    for (int kk = 0; kk < 64; kk += 32) {
      const int kof = kk + (lane >> 4) * 8;
      bf16x8_t af[4], bfr[4];
#pragma unroll
      for (int i = 0; i < 4; i++) {
        af[i] = __builtin_bit_cast(bf16x8_t,
            *(const short8_t*)(As + (wm + i * 16 + (lane & 15)) * LDT + kof));
        bfr[i] = __builtin_bit_cast(bf16x8_t,
            *(const short8_t*)(Bs + (wn + i * 16 + (lane & 15)) * LDT + kof));
      }
#pragma unroll
      for (int i = 0; i < 4; i++)
#pragma unroll
        for (int j = 0; j < 4; j++)
          acc[i][j] = __builtin_amdgcn_mfma_f32_16x16x32_bf16(
              af[i], bfr[j], acc[i][j], 0, 0, 0);
    }
    __syncthreads();
  }
#pragma unroll
  for (int i = 0; i < 4; i++) {
    int row = row0 + wm + i * 16 + ((lane >> 4) * 4);
#pragma unroll
    for (int j = 0; j < 4; j++) {
      int col = col0 + wn + j * 16 + (lane & 15);
      float bv = bias ? bias[col] * bias_scale : 0.f;
#pragma unroll
      for (int r = 0; r < 4; r++) {
        float v = acc[i][j][r] + bv;
        size_t off = (size_t)(row + r) * c_stride + c_coloff + col;
        if (Cf) Cf[off] = v;
        else Cb[off] = f2bf(v);
      }
    }
  }
}

// ---------- primary top-k: SUBL lanes per cell-sorted a-point ----------
// Each lane scans every SUBL-th candidate of the 3x3x3 neighborhood
// (adjacent lanes hit adjacent uint2 -> coalesced), then an aligned
// shfl-XOR butterfly merges the SUBL disjoint top-8 sets exactly.
// Exact iff merged 8th-best d2 <= 288 (outside neighborhood => d2 >= 289);
// sentinel keys exceed that, so <8 candidates also routes to fallback.
__global__ __launch_bounds__(256) void topk_bins(
    const unsigned* __restrict__ boff, const uint2* __restrict__ bcj,
    const uint2* __restrict__ acj, int* __restrict__ idxb,
    float* __restrict__ dwb, unsigned* __restrict__ failcnt,
    unsigned* __restrict__ faillist) {
  const int tid = blockIdx.x * 256 + threadIdx.x;
  const int t = tid / SUBL;        // cell-sorted a index
  const int sub = tid & (SUBL - 1);
  const uint2 av = acj[t];
  const int batch = t >> 13;  // batches are contiguous in cell order
  const int ax = av.x & 127, ay = (av.x >> 7) & 127, az = (av.x >> 14) & 127;
  const int cx = ax >> 4, cy = ay >> 4, cz = az >> 4;
  const int xlo = max(cx - 1, 0), xhi = min(cx + 1, 7);
  const int ylo = max(cy - 1, 0), yhi = min(cy + 1, 7);
  const int zlo = max(cz - 1, 0), zhi1 = min(cz + 1, 7) + 1;
  unsigned k[8];
#pragma unroll
  for (int s = 0; s < 8; s++) k[s] = 0xFFFFFFF8u + s;
  for (int nx = xlo; nx <= xhi; nx++) {
    for (int ny = ylo; ny <= yhi; ny++) {
      const int cb = (batch << 9) | (nx << 6) | (ny << 3);
      const int gs = (int)boff[cb + zlo];
      const int ge = (int)boff[cb + zhi1];
      for (int i = gs + sub; i < ge; i += SUBL) {
        const uint2 b = bcj[i];
        const int dx = ax - (int)(b.x & 127);
        const int dy = ay - (int)((b.x >> 7) & 127);
        const int dz = az - (int)((b.x >> 14) & 127);
        const unsigned d2 = (unsigned)(__mul24(dx, dx) + __mul24(dy, dy) +
                                       __mul24(dz, dz));
        kins(k, (d2 << 13) | b.y);
      }
    }
  }
  const int lane = threadIdx.x & 63;
#pragma unroll
  for (int half = 1; half < SUBL; half <<= 1) {
    unsigned o[8];
#pragma unroll
    for (int s = 0; s < 8; s++)
      o[s] = (unsigned)__shfl((int)k[s], lane ^ half, 64);
#pragma unroll
    for (int s = 0; s < 8; s++) kins(k, o[s]);
  }
  if (sub == 0) {
    const int g = (batch << 13) | (int)av.y;
#pragma unroll
    for (int s = 0; s < 8; s++) {
      unsigned key = k[s];
      idxb[(size_t)g * 8 + s] = (int)(key & 8191u);
      float dist = sqrtf((float)(key >> 13)) * (1.0f / 128.0f);
      dwb[(size_t)g * 8 + s] = 0.5f - fminf(dist, 0.5f);
    }
    if (k[7] >= (289u << 13)) {
      unsigned fp = atomicAdd(failcnt, 1u);
      faillist[fp] = (unsigned)g;
    }
  }
}

// ---------- fallback: exact full scan, one wave per failed a-point ----------
__global__ __launch_bounds__(256) void topk_fallback(
    const unsigned* __restrict__ failcnt, const unsigned* __restrict__ faillist,
    const uint2* __restrict__ bcj, const unsigned* __restrict__ apk,
    int* __restrict__ idxb, float* __restrict__ dwb) {
  const int wave = (blockIdx.x * 256 + threadIdx.x) >> 6;  // 0..511
  const int lane = threadIdx.x & 63;
  const unsigned nf = *failcnt;
  for (unsigned fi = wave; fi < nf; fi += 512) {
    const unsigned g = faillist[fi];
    const int batch = (int)(g >> 13);
    const unsigned av = apk[g];
    const int ax = av & 127, ay = (av >> 7) & 127, az = (av >> 14) & 127;
    const uint2* pb = bcj + ((size_t)batch << 13);
    unsigned k[8];
#pragma unroll
    for (int s = 0; s < 8; s++) k[s] = 0xFFFFFFF8u + s;
    for (int i = lane; i < NB; i += 64) {
      const uint2 b = pb[i];
      const int dx = ax - (int)(b.x & 127);
      const int dy = ay - (int)((b.x >> 7) & 127);
      const int dz = az - (int)((b.x >> 14) & 127);
      const unsigned d2 = (unsigned)(__mul24(dx, dx) + __mul24(dy, dy) +
                                     __mul24(dz, dz));
      kins(k, (d2 << 13) | b.y);
    }
#pragma unroll
    for (int half = 32; half >= 1; half >>= 1) {
      unsigned o[8];
#pragma unroll
      for (int s = 0; s < 8; s++)
        o[s] = (unsigned)__shfl((int)k[s], lane ^ half, 64);
#pragma unroll
      for (int s = 0; s < 8; s++) kins(k, o[s]);
    }
    if (lane == 0) {
#pragma unroll
      for (int s = 0; s < 8; s++) {
        unsigned key = k[s];
        idxb[(size_t)g * 8 + s] = (int)(key & 8191u);
        float dist = sqrtf((float)(key >> 13)) * (1.0f / 128.0f);
        dwb[(size_t)g * 8 + s] = 0.5f - fminf(dist, 0.5f);
      }
    }
  }
}

// ---------- fuse: hsum = sum_k relu(Pa + Pb[idx_k]) * dw_k ; copy a row ----------
__global__ __launch_bounds__(256) void fuse_kernel(
    const unsigned short* __restrict__ Pa, const unsigned short* __restrict__ Pb,
    const int* __restrict__ idxb, const float* __restrict__ dwb,
    const float* __restrict__ a_feats, unsigned short* __restrict__ H,
    float* __restrict__ outp) {
  const int g = blockIdx.x * 4 + (threadIdx.x >> 6);
  const int lane = threadIdx.x & 63;
  const int batch = g >> 13;
  const size_t fo = (size_t)g * 256 + lane * 4;
  ushort4 pav = *(const ushort4*)(Pa + fo);
  const float pa0 = bf2f(pav.x), pa1 = bf2f(pav.y), pa2 = bf2f(pav.z),
              pa3 = bf2f(pav.w);
  float h0 = 0.f, h1 = 0.f, h2 = 0.f, h3 = 0.f;
  const size_t bbase = (size_t)(batch << 13) * 256;
#pragma unroll
  for (int k = 0; k < 8; k++) {
    const int j = idxb[(size_t)g * 8 + k];
    const float w = dwb[(size_t)g * 8 + k];
    const ushort4 pbv =
        *(const ushort4*)(Pb + bbase + (size_t)j * 256 + lane * 4);
    h0 += fmaxf(pa0 + bf2f(pbv.x), 0.f) * w;
    h1 += fmaxf(pa1 + bf2f(pbv.y), 0.f) * w;
    h2 += fmaxf(pa2 + bf2f(pbv.z), 0.f) * w;
    h3 += fmaxf(pa3 + bf2f(pbv.w), 0.f) * w;
  }
  ushort4 hv;
  hv.x = f2bf(h0); hv.y = f2bf(h1); hv.z = f2bf(h2); hv.w = f2bf(h3);
  *(ushort4*)(H + fo) = hv;
  float4 av = *(const float4*)(a_feats + fo);
  *(float4*)(outp + (size_t)g * 512 + lane * 4) = av;
}

// ---------- launch ----------
extern "C" void kernel_launch(void* const* d_in, const int* in_sizes, int n_in,
                              void* d_out, int out_size, void* d_ws,
                              size_t ws_size, hipStream_t stream) {
  const float* a_feats = (const float*)d_in[0];
  const float* b_feats = (const float*)d_in[1];
  const int* coords_a = (const int*)d_in[2];
  const int* coords_b = (const int*)d_in[3];
  const float* w1 = (const float*)d_in[4];
  const float* b1 = (const float*)d_in[5];
  const float* w2 = (const float*)d_in[6];
  const float* b2 = (const float*)d_in[7];
  float* outp = (float*)d_out;

  char* p = (char*)d_ws;
  auto take = [&](size_t bytes) {
    char* r = p;
    p += (bytes + 255) & ~(size_t)255;
    return r;
  };
  unsigned short* Ab = (unsigned short*)take((size_t)NPTS * DIM * 2);
  unsigned short* Bb = (unsigned short*)take((size_t)NPTS * DIM * 2);
  unsigned short* Pa = (unsigned short*)take((size_t)NPTS * DIM * 2);
  unsigned short* Pb = (unsigned short*)take((size_t)NPTS * DIM * 2);
  unsigned short* Hb = (unsigned short*)take((size_t)NPTS * DIM * 2);
  int* idxb = (int*)take((size_t)NPTS * 8 * 4);
  float* dwb = (float*)take((size_t)NPTS * 8 * 4);
  unsigned* bpk = (unsigned*)take((size_t)NPTS * 4);
  unsigned* apk = (unsigned*)take((size_t)NPTS * 4);
  unsigned* bcnt = (unsigned*)take(NCELL * 4);
  unsigned* acnt = (unsigned*)take(NCELL * 4);
  unsigned* bcur = (unsigned*)take(NCELL * 4);
  unsigned* acur = (unsigned*)take(NCELL * 4);
  unsigned* boff = (unsigned*)take((NCELL + 1) * 4);
  unsigned* aoff = (unsigned*)take((NCELL + 1) * 4);
  uint2* bcj = (uint2*)take((size_t)NPTS * 8);
  uint2* acj = (uint2*)take((size_t)NPTS * 8);
  unsigned* failcnt = (unsigned*)take(256);
  unsigned* faillist = (unsigned*)take((size_t)NPTS * 4);
  unsigned short* Wdiff = (unsigned short*)take(256 * 256 * 2);
  unsigned short* Wb16 = (unsigned short*)take(256 * 256 * 2);
  unsigned short* W2b = (unsigned short*)take(256 * 256 * 2);

  prep_weights<<<256, 256, 0, stream>>>(w1, w2, Wdiff, Wb16, W2b);
  cvt_f32_bf16<<<NPTS * DIM / 1024, 256, 0, stream>>>(a_feats, Ab);
  cvt_f32_bf16<<<NPTS * DIM / 1024, 256, 0, stream>>>(b_feats, Bb);

  zero_counts<<<NCELL / 256, 256, 0, stream>>>(bcnt, acnt, failcnt);
  pack_count<<<NPTS / 256, 256, 0, stream>>>(coords_b, bpk, bcnt);
  pack_count<<<NPTS / 256, 256, 0, stream>>>(coords_a, apk, acnt);
  scan_cells<<<1, 256, 0, stream>>>(bcnt, acnt, boff, aoff, bcur, acur);
  scatter_pts<<<NPTS / 256, 256, 0, stream>>>(bpk, bcur, bcj);
  scatter_pts<<<NPTS / 256, 256, 0, stream>>>(apk, acur, acj);

  // Pa = A @ Wb^T + b1 (bf16 out) ; Pb = B @ Wdiff^T (bf16 out)
  gemm_bf16<<<dim3(NPTS / 128, 2), 256, 0, stream>>>(
      (const short*)Ab, (const short*)Wb16, nullptr, Pa, b1, 1.0f, 256, 0);
  gemm_bf16<<<dim3(NPTS / 128, 2), 256, 0, stream>>>(
      (const short*)Bb, (const short*)Wdiff, nullptr, Pb, nullptr, 0.0f, 256, 0);

  topk_bins<<<NPTS * SUBL / 256, 256, 0, stream>>>(boff, bcj, acj, idxb, dwb,
                                                   failcnt, faillist);
  topk_fallback<<<128, 256, 0, stream>>>(failcnt, faillist, bcj, apk, idxb,
                                         dwb);

  fuse_kernel<<<NPTS / 4, 256, 0, stream>>>(Pa, Pb, idxb, dwb, a_feats, Hb,
                                            outp);

  // out[:, :, 256:512] = H @ w2^T + 8*b2
  gemm_bf16<<<dim3(NPTS / 128, 2), 256, 0, stream>>>(
      (const short*)Hb, (const short*)W2b, outp, nullptr, b2, 8.0f, 512, 256);
}